// Round 10
// baseline (337.111 us; speedup 1.0000x reference)
//
#include <hip/hip_runtime.h>

typedef unsigned short u16;
typedef __attribute__((ext_vector_type(4))) float f32x4;
typedef __attribute__((ext_vector_type(16))) float f32x16;
typedef __attribute__((ext_vector_type(8))) __bf16 bf16x8;

// ---------- helpers ----------
__device__ __forceinline__ u16 f2bf(float f) {
    unsigned int x = __float_as_uint(f);
    x += 0x7fffu + ((x >> 16) & 1u);          // RNE
    return (u16)(x >> 16);
}
__device__ __forceinline__ float bf2f(u16 u) {
    return __uint_as_float(((unsigned int)u) << 16);
}
__device__ __forceinline__ void async16(const void* g, void* l) {
    __builtin_amdgcn_global_load_lds(
        (const __attribute__((address_space(1))) void*)g,
        (__attribute__((address_space(3))) void*)l,
        16, 0, 0);
}
__device__ __forceinline__ void barrier_fence() {
    asm volatile("" ::: "memory");
    __builtin_amdgcn_s_barrier();
    asm volatile("" ::: "memory");
}
__device__ __forceinline__ unsigned cvtpk(float lo, float hi) {
    unsigned d;
    asm("v_cvt_pk_bf16_f32 %0, %1, %2" : "=v"(d) : "v"(lo), "v"(hi));
    return d;
}
// P-row (16 f32, lane-local) -> 32x32 MFMA A-fragment (verified in round-7 v2)
__device__ __forceinline__ bf16x8 build_pa(const float* p) {
    unsigned A0 = cvtpk(p[0], p[1]);
    unsigned A1 = cvtpk(p[2], p[3]);
    unsigned B0 = cvtpk(p[4], p[5]);
    unsigned B1 = cvtpk(p[6], p[7]);
    asm volatile("v_permlane32_swap_b32 %0, %1" : "+v"(A0), "+v"(B0));
    asm volatile("v_permlane32_swap_b32 %0, %1" : "+v"(A1), "+v"(B1));
    union { unsigned u[4]; bf16x8 v; } pu;
    pu.u[0] = A0; pu.u[1] = A1; pu.u[2] = B0; pu.u[3] = B1;
    return pu.v;
}

// ---------- fp32 -> bf16 convert, all four inputs in one launch ----------
__global__ __launch_bounds__(256)
void cvt_all(const float* __restrict__ x,  const float* __restrict__ wq,
             const float* __restrict__ wkv, const float* __restrict__ wo,
             u16* __restrict__ xb, u16* __restrict__ wqb,
             u16* __restrict__ wkvb, u16* __restrict__ wob)
{
    const int nx = 8388608, nq = 4194304, nkv = 2097152;
    const int i = (blockIdx.x * 256 + threadIdx.x) * 4;
    const float* src; u16* dst; int off;
    if (i < nx)                 { src = x;   dst = xb;   off = i; }
    else if (i < nx + nq)       { src = wq;  dst = wqb;  off = i - nx; }
    else if (i < nx + nq + nkv) { src = wkv; dst = wkvb; off = i - nx - nq; }
    else                        { src = wo;  dst = wob;  off = i - nx - nq - nkv; }
    const float4 v = *(const float4*)(src + off);
    ushort4 o;
    o.x = f2bf(v.x); o.y = f2bf(v.y); o.z = f2bf(v.z); o.w = f2bf(v.w);
    *(ushort4*)(dst + off) = o;
}

// ---------- GEMM1 + fused RoPE: qkv = x * [Wq|Wkv]^T (round-6, frozen) -----
__global__ __launch_bounds__(256, 3)
void gemm_qkv(const u16* __restrict__ A,
              const u16* __restrict__ B0,
              const u16* __restrict__ B1,
              u16* __restrict__ C,
              u16* __restrict__ vbuf,
              int M, int K)
{
    constexpr int ASZ = 128 * 32;        // u16 per buffer (8 KB)
    __shared__ __align__(16) u16 As[3 * ASZ];
    __shared__ __align__(16) u16 Bs[3 * ASZ];

    const int tid  = threadIdx.x;
    const int w    = tid >> 6;
    const int lane = tid & 63;
    const int fl   = lane & 15;
    const int q4   = lane >> 4;
    const int wm   = w >> 1;             // 0..1 : 64-row slice
    const int wn   = w & 1;              // 0..1 : column group

    const int gx  = gridDim.x;           // 24
    const int nwg = gx * gridDim.y;
    int id = blockIdx.y * gx + blockIdx.x;
    id = (id & 7) * (nwg >> 3) + (id >> 3);
    const int m0 = (id / gx) * 128;
    const int n0 = (id % gx) * 128;

    const u16* Bp = B0;
    int nb = n0;
    if (n0 >= 2048) { Bp = B1; nb = n0 - 2048; }

    const int srow = w * 16 + (lane >> 2);
    const int sg   = (lane & 3) ^ ((lane >> 3) & 3);
    const u16* agp = A  + (size_t)(m0 + srow) * K + sg * 8;
    const u16* bgp = Bp + (size_t)(nb + srow) * K + sg * 8;
    const int sLds = w * 512;

    const int cSlot = (q4 ^ ((fl >> 1) & 3)) * 8;

    f32x4 acc[4][4];
    #pragma unroll
    for (int i = 0; i < 4; ++i)
        #pragma unroll
        for (int j = 0; j < 4; ++j)
            acc[i][j] = f32x4{0.f, 0.f, 0.f, 0.f};

    const int NT = K >> 5;               // 64 K-steps

    auto stage = [&](int t, int bf) {
        const size_t kof = (size_t)t * 32;
        async16(agp + kof,                   &As[bf * ASZ + sLds]);
        async16(agp + (size_t)64 * K + kof,  &As[bf * ASZ + 2048 + sLds]);
        async16(bgp + kof,                   &Bs[bf * ASZ + sLds]);
        async16(bgp + (size_t)64 * K + kof,  &Bs[bf * ASZ + 2048 + sLds]);
    };

    stage(0, 0);
    stage(1, 1);

    int bf = 0;
    for (int t = 0; t < NT; ++t) {
        if (t < NT - 1) asm volatile("s_waitcnt vmcnt(4)" ::: "memory");
        else            asm volatile("s_waitcnt vmcnt(0)" ::: "memory");
        barrier_fence();
        const int bf2 = (bf + 2 >= 3) ? bf - 1 : bf + 2;
        if (t + 2 < NT) stage(t + 2, bf2);

        const int ab = bf * ASZ + (wm * 64 + fl) * 32 + cSlot;
        // B rows for frag j: wn*32 + (j&1)*16 + (j>>1)*64 + fl
        const int bb = bf * ASZ + (wn * 32 + fl) * 32 + cSlot;
        bf16x8 a[4], b[4];
        #pragma unroll
        for (int mt = 0; mt < 4; ++mt)
            a[mt] = *(const bf16x8*)&As[ab + mt * 512];
        b[0] = *(const bf16x8*)&Bs[bb];
        b[1] = *(const bf16x8*)&Bs[bb + 512];
        b[2] = *(const bf16x8*)&Bs[bb + 2048];
        b[3] = *(const bf16x8*)&Bs[bb + 2560];

        #pragma unroll
        for (int mt = 0; mt < 4; ++mt)
            #pragma unroll
            for (int nt = 0; nt < 4; ++nt)
                acc[mt][nt] = __builtin_amdgcn_mfma_f32_16x16x32_bf16(
                    a[mt], b[nt], acc[mt][nt], 0, 0, 0);

        bf = (bf + 1 >= 3) ? 0 : bf + 1;
    }

    // ---- epilogue: fused RoPE for q/k blocks; vbuf scatter for v ----
    if (n0 < 2560) {
        const float sc = (n0 < 2048) ? 0.08838834764831845f : 1.0f;
        float inv[2];
        #pragma unroll
        for (int j = 0; j < 2; ++j)
            inv[j] = exp2f(-(float)(wn * 32 + j * 16 + fl) * 0.2076205f); // log2(1e4)/64
        #pragma unroll
        for (int mt = 0; mt < 4; ++mt) {
            #pragma unroll
            for (int r = 0; r < 4; ++r) {
                const int row = m0 + wm * 64 + mt * 16 + q4 * 4 + r;
                const float pos = (float)(row & 2047);
                #pragma unroll
                for (int j = 0; j < 2; ++j) {
                    float s, c;
                    __sincosf(pos * inv[j], &s, &c);
                    const float x1 = acc[mt][j][r];
                    const float x2 = acc[mt][j + 2][r];
                    const int i0 = wn * 32 + j * 16 + fl;
                    C[(size_t)row * 3072 + n0 + i0]      = f2bf((x1 * c - x2 * s) * sc);
                    C[(size_t)row * 3072 + n0 + 64 + i0] = f2bf((x2 * c + x1 * s) * sc);
                }
            }
        }
    } else {
        #pragma unroll
        for (int mt = 0; mt < 4; ++mt)
            #pragma unroll
            for (int j = 0; j < 4; ++j) {
                const int colb = n0 + wn * 32 + (j & 1) * 16 + (j >> 1) * 64 + fl;
                const int f = colb - 2560;
                #pragma unroll
                for (int r = 0; r < 4; ++r) {
                    const int row = m0 + wm * 64 + mt * 16 + q4 * 4 + r;
                    const int tt = row & 2047;
                    const int bb2 = row >> 11;
                    vbuf[((size_t)((bb2 << 2) + (f >> 7)) * 128 + (f & 127)) * 2048 + tt] =
                        f2bf(acc[mt][j][r]);
                }
            }
    }
}

// ---------- GEMM2: Cf = A[M,K] * B[N,K]^T, 128x128 (round-4, frozen) -------
__global__ __launch_bounds__(256, 3)
void gemm128r(const u16* __restrict__ A,
              const u16* __restrict__ B0,
              float* __restrict__ Cf,
              int M, int N, int K)
{
    constexpr int ASZ = 128 * 32;
    __shared__ __align__(16) u16 As[3 * ASZ];
    __shared__ __align__(16) u16 Bs[3 * ASZ];

    const int tid  = threadIdx.x;
    const int w    = tid >> 6;
    const int lane = tid & 63;
    const int fl   = lane & 15;
    const int q4   = lane >> 4;
    const int wm   = w >> 1;
    const int wn   = w & 1;

    const int gx  = gridDim.x;
    const int nwg = gx * gridDim.y;
    int id = blockIdx.y * gx + blockIdx.x;
    id = (id & 7) * (nwg >> 3) + (id >> 3);
    const int m0 = (id / gx) * 128;
    const int n0 = (id % gx) * 128;

    const int srow = w * 16 + (lane >> 2);
    const int sg   = (lane & 3) ^ ((lane >> 3) & 3);
    const u16* agp = A  + (size_t)(m0 + srow) * K + sg * 8;
    const u16* bgp = B0 + (size_t)(n0 + srow) * K + sg * 8;
    const int sLds = w * 512;

    const int cSlot = (q4 ^ ((fl >> 1) & 3)) * 8;

    f32x4 acc[4][4];
    #pragma unroll
    for (int i = 0; i < 4; ++i)
        #pragma unroll
        for (int j = 0; j < 4; ++j)
            acc[i][j] = f32x4{0.f, 0.f, 0.f, 0.f};

    const int NT = K >> 5;

    auto stage = [&](int t, int bf) {
        const size_t kof = (size_t)t * 32;
        async16(agp + kof,                   &As[bf * ASZ + sLds]);
        async16(agp + (size_t)64 * K + kof,  &As[bf * ASZ + 2048 + sLds]);
        async16(bgp + kof,                   &Bs[bf * ASZ + sLds]);
        async16(bgp + (size_t)64 * K + kof,  &Bs[bf * ASZ + 2048 + sLds]);
    };

    stage(0, 0);
    stage(1, 1);

    int bf = 0;
    for (int t = 0; t < NT; ++t) {
        if (t < NT - 1) asm volatile("s_waitcnt vmcnt(4)" ::: "memory");
        else            asm volatile("s_waitcnt vmcnt(0)" ::: "memory");
        barrier_fence();
        const int bf2 = (bf + 2 >= 3) ? bf - 1 : bf + 2;
        if (t + 2 < NT) stage(t + 2, bf2);

        const int ab = bf * ASZ + (wm * 64 + fl) * 32 + cSlot;
        const int bb = bf * ASZ + (wn * 64 + fl) * 32 + cSlot;
        bf16x8 a[4], b[4];
        #pragma unroll
        for (int mt = 0; mt < 4; ++mt)
            a[mt] = *(const bf16x8*)&As[ab + mt * 512];
        #pragma unroll
        for (int nt = 0; nt < 4; ++nt)
            b[nt] = *(const bf16x8*)&Bs[bb + nt * 512];

        #pragma unroll
        for (int mt = 0; mt < 4; ++mt)
            #pragma unroll
            for (int nt = 0; nt < 4; ++nt)
                acc[mt][nt] = __builtin_amdgcn_mfma_f32_16x16x32_bf16(
                    a[mt], b[nt], acc[mt][nt], 0, 0, 0);

        bf = (bf + 1 >= 3) ? 0 : bf + 1;
    }

    #pragma unroll
    for (int mt = 0; mt < 4; ++mt)
        #pragma unroll
        for (int nt = 0; nt < 4; ++nt) {
            const int colb = n0 + wn * 64 + nt * 16 + fl;
            #pragma unroll
            for (int r = 0; r < 4; ++r) {
                const int row = m0 + wm * 64 + mt * 16 + q4 * 4 + r;
                Cf[(size_t)row * N + colb] = acc[mt][nt][r];
            }
        }
}

// ---------- causal flash attention v3: dual-ctx 32x32, shared K/V reads ----
// Block = 4 waves x 32 q-rows x 2 contexts: wave w owns rows lo*128+w*32
// (ctx0) AND hi*128+w*32 (ctx1), hi = 15-lo -> per-block work constant.
// Each K (aK) and V (bv) LDS b128 read feeds BOTH contexts' 32x32 MFMAs
// (~2x FLOP/LDS-byte vs prior attn); in-register P via cvt_pk+permlane
// (round-7-verified fragments) -> no Ps buffer, no lgkmcnt serialization.
// KVBLK=32; 3 rotating LDS buffers with counted vmcnt(4) (never drains in
// steady state; gemm128r-proven rotation). Grid 256 = 1 block/CU; id
// mapping clusters all blocks of one (b,kvh) on one XCD (K/V L2-resident).
__global__ __launch_bounds__(256, 1)
void attn_kernel(const u16* __restrict__ qkv,
                 const u16* __restrict__ vsrc,
                 u16* __restrict__ y)
{
    constexpr int T = 2048;
    const int id  = blockIdx.x;            // 0..255
    const int p   = id & 7;                // (b,kvh) group -> XCD cluster
    const int bh  = p * 4 + ((id >> 3) & 3);
    const int lp  = id >> 5;               // 0..7
    const int lo  = lp;
    const int hi  = 15 - lp;
    const int b   = bh >> 4, h = bh & 15, kvh = h >> 2;

    const int tid  = threadIdx.x;
    const int w    = tid >> 6;             // 0..3
    const int lane = tid & 63;
    const int l31  = lane & 31;
    const int hh   = lane >> 5;

    __shared__ __align__(16) u16 Ks[3][32 * 128];   // [kv][d] swizzled, 8KB/buf
    __shared__ __align__(16) u16 Vt[3][128 * 32];   // [d][kv] swizzled, 8KB/buf

    const u16* Qg = qkv  + (size_t)(b * T) * 3072 + (h << 7);
    const u16* Kg = qkv  + (size_t)(b * T) * 3072 + 2048 + (kvh << 7);
    const u16* Vg = vsrc + (size_t)((b * 4 + kvh) * 128) * T;

    // Q fragments (B-operand), both contexts; pre-scaled by 1/sqrt(D)
    const int q0 = lo * 128 + w * 32;
    const int q1 = hi * 128 + w * 32;
    bf16x8 qf0[8], qf1[8];
    #pragma unroll
    for (int kc = 0; kc < 8; ++kc) {
        qf0[kc] = *(const bf16x8*)&Qg[(size_t)(q0 + l31) * 3072 + kc * 16 + hh * 8];
        qf1[kc] = *(const bf16x8*)&Qg[(size_t)(q1 + l31) * 3072 + kc * 16 + hh * 8];
    }

    // staging: 8 chunks of 1KB per tile; source pre-swizzled, LDS dest linear
    int goffK[2], goffV[2], ldsC[2];
    #pragma unroll
    for (int i = 0; i < 2; ++i) {
        const int c  = w + 4 * i;                 // 0..7
        const int rk = 4 * c + (lane >> 4);       // K row 0..31
        const int lk = (lane & 15) ^ (rk & 15);
        goffK[i] = rk * 3072 + lk * 8;
        const int rv = 16 * c + (lane >> 2);      // V row (d) 0..127
        const int lv = (lane & 3) ^ ((lane >> 3) & 3);   // = (lane&3)^((rv>>1)&3)
        goffV[i] = rv * T + lv * 8;
        ldsC[i]  = c * 512;
    }

    auto stage = [&](int t, int bf) {             // 4 gloads per thread
        const u16* kb = Kg + (size_t)t * 32 * 3072;
        const u16* vb = Vg + t * 32;
        #pragma unroll
        for (int i = 0; i < 2; ++i) {
            async16(kb + goffK[i], &Ks[bf][ldsC[i]]);
            async16(vb + goffV[i], &Vt[bf][ldsC[i]]);
        }
    };

    f32x16 o0[4], o1[4];
    #pragma unroll
    for (int dt = 0; dt < 4; ++dt)
        #pragma unroll
        for (int r = 0; r < 16; ++r) { o0[dt][r] = 0.f; o1[dt][r] = 0.f; }
    float ls0 = 0.f, ls1 = 0.f;

    const int NJ  = 4 * hi + 4;
    const int jw0 = 4 * lo + w;                   // ctx0 diagonal kv-tile
    const int jw1 = 4 * hi + w;                   // ctx1 diagonal kv-tile
    const int aswz = l31 & 15;
    const int vswz = (l31 >> 1) & 3;

    stage(0, 0);
    stage(1, 1);
    int bf = 0;
    for (int j = 0; j < NJ; ++j) {
        if (j < NJ - 1) asm volatile("s_waitcnt vmcnt(4)" ::: "memory");
        else            asm volatile("s_waitcnt vmcnt(0)" ::: "memory");
        barrier_fence();                          // tile j visible; buf j+2 free
        const int bf2 = (bf + 2 >= 3) ? bf - 1 : bf + 2;
        if (j + 2 < NJ) stage(j + 2, bf2);

        const bool a0 = (j <= jw0);               // wave-uniform
        const bool a1 = (j <= jw1);
        if (a0 || a1) {
            // S^T = K * Q^T: rows = kv (regs), cols = q (= l31); shared aK
            f32x16 s0, s1;
            #pragma unroll
            for (int r = 0; r < 16; ++r) { s0[r] = 0.f; s1[r] = 0.f; }
            #pragma unroll
            for (int kc = 0; kc < 8; ++kc) {
                bf16x8 aK = *(const bf16x8*)
                    &Ks[bf][l31 * 128 + ((2 * kc + hh) ^ aswz) * 8];
                if (a1) s1 = __builtin_amdgcn_mfma_f32_32x32x16_bf16(aK, qf1[kc], s1, 0, 0, 0);
                if (a0) s0 = __builtin_amdgcn_mfma_f32_32x32x16_bf16(aK, qf0[kc], s0, 0, 0, 0);
            }
            if (j == jw1) {
                #pragma unroll
                for (int r = 0; r < 16; ++r) {
                    const int kvl = (r & 3) + 8 * (r >> 2) + 4 * hh;
                    if (kvl > l31) s1[r] = -3e38f;
                }
            }
            if (j == jw0) {
                #pragma unroll
                for (int r = 0; r < 16; ++r) {
                    const int kvl = (r & 3) + 8 * (r >> 2) + 4 * hh;
                    if (kvl > l31) s0[r] = -3e38f;
                }
            }

            // exp + in-register P->A fragments (round-7-verified path)
            bf16x8 pA0[2], pA1[2];
            if (a1) {
                float pr[16];
                #pragma unroll
                for (int r = 0; r < 16; ++r) { pr[r] = __expf(s1[r]); ls1 += pr[r]; }
                pA1[0] = build_pa(&pr[0]);
                pA1[1] = build_pa(&pr[8]);
            }
            if (a0) {
                float pr[16];
                #pragma unroll
                for (int r = 0; r < 16; ++r) { pr[r] = __expf(s0[r]); ls0 += pr[r]; }
                pA0[0] = build_pa(&pr[0]);
                pA0[1] = build_pa(&pr[8]);
            }

            // PV: shared bv reads feed both contexts
            #pragma unroll
            for (int kc = 0; kc < 2; ++kc)
                #pragma unroll
                for (int dt = 0; dt < 4; ++dt) {
                    bf16x8 bv = *(const bf16x8*)
                        &Vt[bf][(dt * 32 + l31) * 32 + ((2 * kc + hh) ^ vswz) * 8];
                    if (a1) o1[dt] = __builtin_amdgcn_mfma_f32_32x32x16_bf16(pA1[kc], bv, o1[dt], 0, 0, 0);
                    if (a0) o0[dt] = __builtin_amdgcn_mfma_f32_32x32x16_bf16(pA0[kc], bv, o0[dt], 0, 0, 0);
                }
        }
        bf = (bf + 1 >= 3) ? 0 : bf + 1;
    }

    // l reductions + stores, both contexts
    ls0 += __shfl_xor(ls0, 32, 64);
    ls1 += __shfl_xor(ls1, 32, 64);
    const float li0 = 1.0f / ls0;
    const float li1 = 1.0f / ls1;

    #pragma unroll
    for (int r = 0; r < 16; ++r) {
        const int qloc = (r & 3) + 8 * (r >> 2) + 4 * hh;
        const float lr0 = __shfl(li0, qloc, 64);
        const float lr1 = __shfl(li1, qloc, 64);
        const size_t row0 = (size_t)(b * T + q0 + qloc);
        const size_t row1 = (size_t)(b * T + q1 + qloc);
        #pragma unroll
        for (int dt = 0; dt < 4; ++dt) {
            y[row0 * 2048 + (h << 7) + dt * 32 + l31] = f2bf(o0[dt][r] * lr0);
            y[row1 * 2048 + (h << 7) + dt * 32 + l31] = f2bf(o1[dt][r] * lr1);
        }
    }
}

// ---------- launch ----------------------------------------------------------
extern "C" void kernel_launch(void* const* d_in, const int* in_sizes, int n_in,
                              void* d_out, int out_size, void* d_ws, size_t ws_size,
                              hipStream_t stream)
{
    const float* x   = (const float*)d_in[0];
    const float* Wq  = (const float*)d_in[1];
    const float* Wkv = (const float*)d_in[2];
    const float* Wo  = (const float*)d_in[3];
    float* out = (float*)d_out;

    const int nx = 4096 * 2048, nq = 2048 * 2048, nkv = 1024 * 2048, no = 2048 * 2048;

    u16* xb   = (u16*)d_ws;
    u16* wqb  = xb  + nx;
    u16* wkvb = wqb + nq;
    u16* wob  = wkvb + nkv;
    u16* qkv  = wob + no;                            // [4096, 3072]
    u16* vbuf = qkv + (size_t)4096 * 3072;           // V^T [B*KV*128, 2048]
    u16* y    = vbuf + (size_t)2 * 4 * 128 * 2048;   // [4096, 2048]

    const int ntot = nx + nq + nkv + no;
    cvt_all<<<ntot / 1024, 256, 0, stream>>>(x, Wq, Wkv, Wo, xb, wqb, wkvb, wob);

    dim3 g1(3072 / 128, 4096 / 128);                 // 24 x 32 = 768 wgs (%8==0)
    gemm_qkv<<<g1, 256, 0, stream>>>(xb, wqb, wkvb, qkv, vbuf, 4096, 2048);

    attn_kernel<<<256, 256, 0, stream>>>(qkv, vbuf, y);

    dim3 g2(2048 / 128, 4096 / 128);                 // 16 x 32 = 512 wgs (%8==0)
    gemm128r<<<g2, 256, 0, stream>>>(y, wob, out, 4096, 2048, 2048);
}